// Round 6
// baseline (128.167 us; speedup 1.0000x reference)
//
#include <hip/hip_runtime.h>
#include <hip/hip_bf16.h>

#define N_NODES 25000
#define KFAN    32
#define FIN     256
#define FOUT    256
#define CHUNK_STRIDE (N_NODES * 64)   // ushorts per 64-col chunk of y

typedef float  f32x4  __attribute__((ext_vector_type(4)));
typedef int    i32x4  __attribute__((ext_vector_type(4)));
typedef short  s16x8  __attribute__((ext_vector_type(8)));

// round-to-nearest-even fp32 -> bf16 bits
__device__ __forceinline__ ushort f2bf(float f) {
    unsigned int u = __float_as_uint(f);
    u += 0x7fffu + ((u >> 16) & 1u);
    return (ushort)(u >> 16);
}
__device__ __forceinline__ unsigned int pack2(float a, float b) {
    return (unsigned int)f2bf(a) | ((unsigned int)f2bf(b) << 16);
}

// ---------------- Kernel 0: Wt[n][k] = bf16(W[k][n])  (256x256) ------------
__global__ __launch_bounds__(256) void transpose_w(
    const float* __restrict__ W, ushort* __restrict__ Wt)
{
    __shared__ float ls[32][33];
    const int bid = blockIdx.x;        // 64 blocks
    const int kt  = bid & 7;           // k-tile
    const int nt  = bid >> 3;          // n-tile
    const int t   = threadIdx.x;

    {
        int kl = t >> 3, n4 = (t & 7) * 4;
        float4 v = *(const float4*)(W + (size_t)(kt * 32 + kl) * FOUT + nt * 32 + n4);
        ls[kl][n4 + 0] = v.x; ls[kl][n4 + 1] = v.y;
        ls[kl][n4 + 2] = v.z; ls[kl][n4 + 3] = v.w;
    }
    __syncthreads();
    {
        int nl = t >> 3, k4 = (t & 7) * 4;
        ushort4 o;
        o.x = f2bf(ls[k4 + 0][nl]);
        o.y = f2bf(ls[k4 + 1][nl]);
        o.z = f2bf(ls[k4 + 2][nl]);
        o.w = f2bf(ls[k4 + 3][nl]);
        *(ushort4*)(Wt + (size_t)(nt * 32 + nl) * FIN + kt * 32 + k4) = o;
    }
}

// ---------------- Kernel 1: y = relu(x @ W + b) via MFMA bf16 --------------
// Tile M=64 x N=256 (full width -> x read exactly once). 4 waves; wave wv
// owns cols [wv*64, wv*64+64) = 4 col-tiles; 4 row-tiles => 16 MFMA frags.
// Epilogue writes y in CHUNK-MAJOR layout y[c][n][j] (c=col>>6, j=col&63) so
// each 64-col chunk is a contiguous 3.2MB region (full L2 set utilization).
__global__ __launch_bounds__(256) void gemm_mfma(
    const float*  __restrict__ x,     // [N][FIN] fp32
    const ushort* __restrict__ Wt,    // [FOUT][FIN] bf16 bits (W^T)
    const float*  __restrict__ bias,  // [FOUT]
    ushort*       __restrict__ y)     // chunk-major [4][N][64] bf16 bits
{
    __shared__ ushort As[64][264];    // 33.8 KB; row 528B (16B-aligned, +16B pad)

    const int tid  = threadIdx.x;
    const int lane = tid & 63;
    const int wv   = tid >> 6;
    const int l16  = lane & 15;
    const int q    = lane >> 4;       // quad 0..3
    const int row0 = blockIdx.x * 64;
    const int n0   = wv * 64;

    // ---- stage A: 64 rows x 256 k, fp32->bf16; fully coalesced 16B loads
    #pragma unroll
    for (int i = 0; i < 16; ++i) {
        int row = i * 4 + wv;
        int gr  = row0 + row;
        float4 v = make_float4(0.f, 0.f, 0.f, 0.f);
        if (gr < N_NODES)
            v = *(const float4*)(x + (size_t)gr * FIN + lane * 4);
        uint2 pk;
        pk.x = pack2(v.x, v.y);
        pk.y = pack2(v.z, v.w);
        *(uint2*)&As[row][lane * 4] = pk;
    }
    __syncthreads();

    f32x4 acc[4][4];
    #pragma unroll
    for (int i = 0; i < 4; ++i)
        #pragma unroll
        for (int j = 0; j < 4; ++j) acc[i][j] = (f32x4)0.f;

    #pragma unroll
    for (int ks = 0; ks < 8; ++ks) {
        const int k0 = ks * 32 + q * 8;
        s16x8 a[4], b[4];
        #pragma unroll
        for (int mt = 0; mt < 4; ++mt)
            a[mt] = *(const s16x8*)&As[mt * 16 + l16][k0];
        #pragma unroll
        for (int ct = 0; ct < 4; ++ct)
            b[ct] = *(const s16x8*)(Wt + (size_t)(n0 + ct * 16 + l16) * FIN + k0);
        #pragma unroll
        for (int mt = 0; mt < 4; ++mt)
            #pragma unroll
            for (int ct = 0; ct < 4; ++ct)
                acc[mt][ct] = __builtin_amdgcn_mfma_f32_16x16x32_bf16(a[mt], b[ct], acc[mt][ct], 0, 0, 0);
    }

    // epilogue: +bias, relu, bf16, chunk-major store.
    // D layout: col=lane&15, row=q*4+reg
    #pragma unroll
    for (int ct = 0; ct < 4; ++ct) {
        const int col = n0 + ct * 16 + l16;
        const float bv = bias[col];
        ushort* yc = y + (size_t)(col >> 6) * CHUNK_STRIDE + (col & 63);
        #pragma unroll
        for (int mt = 0; mt < 4; ++mt) {
            #pragma unroll
            for (int rr = 0; rr < 4; ++rr) {
                int row = row0 + mt * 16 + q * 4 + rr;
                if (row < N_NODES)
                    yc[(size_t)row * 64] = f2bf(fmaxf(acc[mt][ct][rr] + bv, 0.f));
            }
        }
    }
}

// ---------------- Kernel 2: out[n][o] = max_k y[neigh[n][k]][o] ------------
// Chunk-major y: chunk c's slice is contiguous 3.2MB (< 4MB L2/XCD, all sets
// usable). chunk = bid&3 pins each chunk to an XCD pair under %8 round-robin.
// 8 lanes/node-group x 16B = one 128B line per gather. neigh loaded
// nontemporally so the stream doesn't evict the resident y slice.
__global__ __launch_bounds__(256) void pool_max(
    const ushort* __restrict__ y,     // chunk-major [4][N][64] bf16 bits
    const int*    __restrict__ neigh, // [N][KFAN]
    float*        __restrict__ out)   // [N][FOUT] fp32
{
    const int bid   = blockIdx.x;
    const int chunk = bid & 3;
    const int nb    = bid >> 2;
    const int tid   = threadIdx.x;
    const int lane  = tid & 63;
    const int g     = lane >> 3;      // node-group within wave (0..7)
    const int gl    = lane & 7;       // lane within group
    const int wv    = tid >> 6;

    const int n  = nb * 32 + wv * 8 + g;
    const int nc = n < N_NODES ? n : N_NODES - 1;

    // group's 32 neighbor indices: lane gl holds idx[4gl .. 4gl+3]
    const i32x4 iv = __builtin_nontemporal_load(
        (const i32x4*)(neigh + (size_t)nc * KFAN + gl * 4));
    const int base8 = lane & 56;
    int ia[4] = {iv.x, iv.y, iv.z, iv.w};

    // hoist all 32 indices into registers (independent shuffles)
    int idx[KFAN];
    #pragma unroll
    for (int k = 0; k < KFAN; ++k)
        idx[k] = __shfl(ia[k & 3], base8 + (k >> 2));

    const ushort* yc = y + (size_t)chunk * CHUNK_STRIDE + gl * 8;

    s16x8 acc = (s16x8)0;
    #pragma unroll
    for (int k = 0; k < KFAN; ++k) {
        s16x8 cur = *(const s16x8*)(yc + (size_t)idx[k] * 64);
        acc = __builtin_elementwise_max(acc, cur);
    }

    if (n < N_NODES) {
        f32x4 o0, o1;
        o0.x = __uint_as_float(((unsigned int)(ushort)acc[0]) << 16);
        o0.y = __uint_as_float(((unsigned int)(ushort)acc[1]) << 16);
        o0.z = __uint_as_float(((unsigned int)(ushort)acc[2]) << 16);
        o0.w = __uint_as_float(((unsigned int)(ushort)acc[3]) << 16);
        o1.x = __uint_as_float(((unsigned int)(ushort)acc[4]) << 16);
        o1.y = __uint_as_float(((unsigned int)(ushort)acc[5]) << 16);
        o1.z = __uint_as_float(((unsigned int)(ushort)acc[6]) << 16);
        o1.w = __uint_as_float(((unsigned int)(ushort)acc[7]) << 16);
        float* op = out + (size_t)n * FOUT + chunk * 64 + gl * 8;
        __builtin_nontemporal_store(o0, (f32x4*)op);
        __builtin_nontemporal_store(o1, (f32x4*)(op + 4));
    }
}

extern "C" void kernel_launch(void* const* d_in, const int* in_sizes, int n_in,
                              void* d_out, int out_size, void* d_ws, size_t ws_size,
                              hipStream_t stream) {
    const float* x     = (const float*)d_in[0];
    const int*   neigh = (const int*)  d_in[1];
    const float* W     = (const float*)d_in[2];
    const float* bias  = (const float*)d_in[3];
    float*       out   = (float*)d_out;
    ushort*      y     = (ushort*)d_ws;    // 12.8 MB of the 256 MiB ws
    // Park W^T (bf16, 128KB) at the front of d_out: gemm reads it, then
    // pool_max fully overwrites d_out afterwards (stream-ordered).
    ushort*      Wt    = (ushort*)d_out;

    transpose_w<<<64, 256, 0, stream>>>(W, Wt);

    const int mblocks = (N_NODES + 63) / 64;               // 391
    gemm_mfma<<<mblocks, 256, 0, stream>>>(x, Wt, bias, y);

    const int nblocks = ((N_NODES + 31) / 32) * 4;         // 782*4 = 3128
    pool_max<<<nblocks, 256, 0, stream>>>(y, neigh, out);
}

// Round 7
// 120.683 us; speedup vs baseline: 1.0620x; 1.0620x over previous
//
#include <hip/hip_runtime.h>
#include <hip/hip_bf16.h>

#define N_NODES 25000
#define KFAN    32
#define FIN     256
#define FOUT    256
#define CHUNK_STRIDE (N_NODES * 64)   // ushorts per 64-col chunk of y

typedef float  f32x4  __attribute__((ext_vector_type(4)));
typedef int    i32x4  __attribute__((ext_vector_type(4)));
typedef short  s16x8  __attribute__((ext_vector_type(8)));

// round-to-nearest-even fp32 -> bf16 bits
__device__ __forceinline__ ushort f2bf(float f) {
    unsigned int u = __float_as_uint(f);
    u += 0x7fffu + ((u >> 16) & 1u);
    return (ushort)(u >> 16);
}
__device__ __forceinline__ unsigned int pack2(float a, float b) {
    return (unsigned int)f2bf(a) | ((unsigned int)f2bf(b) << 16);
}

// ---------------- Kernel 0: Wt[n][k] = bf16(W[k][n])  (256x256) ------------
__global__ __launch_bounds__(256) void transpose_w(
    const float* __restrict__ W, ushort* __restrict__ Wt)
{
    __shared__ float ls[32][33];
    const int bid = blockIdx.x;        // 64 blocks
    const int kt  = bid & 7;           // k-tile
    const int nt  = bid >> 3;          // n-tile
    const int t   = threadIdx.x;

    {
        int kl = t >> 3, n4 = (t & 7) * 4;
        float4 v = *(const float4*)(W + (size_t)(kt * 32 + kl) * FOUT + nt * 32 + n4);
        ls[kl][n4 + 0] = v.x; ls[kl][n4 + 1] = v.y;
        ls[kl][n4 + 2] = v.z; ls[kl][n4 + 3] = v.w;
    }
    __syncthreads();
    {
        int nl = t >> 3, k4 = (t & 7) * 4;
        ushort4 o;
        o.x = f2bf(ls[k4 + 0][nl]);
        o.y = f2bf(ls[k4 + 1][nl]);
        o.z = f2bf(ls[k4 + 2][nl]);
        o.w = f2bf(ls[k4 + 3][nl]);
        *(ushort4*)(Wt + (size_t)(nt * 32 + nl) * FIN + kt * 32 + k4) = o;
    }
}

// ---------------- Kernel 1: y = relu(x @ W + b) via MFMA bf16 --------------
// R4's proven structure: tile M=64 x N=128, grid (391,2) = 782 blocks,
// As 18KB, BK=64 staged loop. ONLY change vs R4: epilogue stores y in
// CHUNK-MAJOR layout y[c][n][j] (c=col>>6, j=col&63) so each 64-col chunk
// is a contiguous 3.2MB region (fits one XCD L2, full set utilization).
__global__ __launch_bounds__(256) void gemm_mfma(
    const float*  __restrict__ x,     // [N][FIN] fp32
    const ushort* __restrict__ Wt,    // [FOUT][FIN] bf16 bits (W^T)
    const float*  __restrict__ bias,  // [FOUT]
    ushort*       __restrict__ y)     // chunk-major [4][N][64] bf16 bits
{
    __shared__ ushort As[64][72];     // 18 KB; rows 144B

    const int tid  = threadIdx.x;
    const int lane = tid & 63;
    const int wv   = tid >> 6;
    const int l16  = lane & 15;
    const int q    = lane >> 4;       // quad 0..3
    const int row0 = blockIdx.x * 64;
    const int n0   = blockIdx.y * 128 + wv * 32;

    f32x4 acc[4][2];
    #pragma unroll
    for (int i = 0; i < 4; ++i)
        #pragma unroll
        for (int j = 0; j < 2; ++j) acc[i][j] = (f32x4)0.f;

    const int r    = tid >> 2;        // 0..63 staging row
    const int kcol = (tid & 3) * 16;  // 0,16,32,48 staging k offset

    for (int kc = 0; kc < FIN; kc += 64) {
        // stage A chunk (64 rows x 64 k) as bf16; each thread 16 k of one row
        float4 v0 = make_float4(0.f,0.f,0.f,0.f), v1 = v0, v2 = v0, v3 = v0;
        int gr = row0 + r;
        if (gr < N_NODES) {
            const float* p = x + (size_t)gr * FIN + kc + kcol;
            v0 = *(const float4*)p;
            v1 = *(const float4*)(p + 4);
            v2 = *(const float4*)(p + 8);
            v3 = *(const float4*)(p + 12);
        }
        uint4 pa, pb;
        pa.x = pack2(v0.x, v0.y); pa.y = pack2(v0.z, v0.w);
        pa.z = pack2(v1.x, v1.y); pa.w = pack2(v1.z, v1.w);
        pb.x = pack2(v2.x, v2.y); pb.y = pack2(v2.z, v2.w);
        pb.z = pack2(v3.x, v3.y); pb.w = pack2(v3.z, v3.w);
        *(uint4*)&As[r][kcol]     = pa;
        *(uint4*)&As[r][kcol + 8] = pb;
        __syncthreads();

        #pragma unroll
        for (int kk = 0; kk < 64; kk += 32) {
            const int k0 = kk + q * 8;
            s16x8 a[4], b[2];
            #pragma unroll
            for (int mt = 0; mt < 4; ++mt)
                a[mt] = *(const s16x8*)&As[mt * 16 + l16][k0];
            #pragma unroll
            for (int ct = 0; ct < 2; ++ct)
                b[ct] = *(const s16x8*)(Wt + (size_t)(n0 + ct * 16 + l16) * FIN + kc + k0);
            #pragma unroll
            for (int mt = 0; mt < 4; ++mt)
                #pragma unroll
                for (int ct = 0; ct < 2; ++ct)
                    acc[mt][ct] = __builtin_amdgcn_mfma_f32_16x16x32_bf16(a[mt], b[ct], acc[mt][ct], 0, 0, 0);
        }
        __syncthreads();
    }

    // epilogue: +bias, relu, bf16, CHUNK-MAJOR store.
    // D layout: col=lane&15, row=q*4+reg
    #pragma unroll
    for (int ct = 0; ct < 2; ++ct) {
        const int col = n0 + ct * 16 + l16;
        const float bv = bias[col];
        ushort* yc = y + (size_t)(col >> 6) * CHUNK_STRIDE + (col & 63);
        #pragma unroll
        for (int mt = 0; mt < 4; ++mt) {
            #pragma unroll
            for (int rr = 0; rr < 4; ++rr) {
                int row = row0 + mt * 16 + q * 4 + rr;
                if (row < N_NODES)
                    yc[(size_t)row * 64] = f2bf(fmaxf(acc[mt][ct][rr] + bv, 0.f));
            }
        }
    }
}

// ---------------- Kernel 2: out[n][o] = max_k y[neigh[n][k]][o] ------------
// Chunk-major y: chunk c's slice is contiguous 3.2MB (< 4MB L2/XCD, all sets
// usable). chunk = bid&3 pins each chunk to an XCD pair under %8 round-robin.
// 8 lanes/node-group x 16B = one 128B line per gather.
__global__ __launch_bounds__(256) void pool_max(
    const ushort* __restrict__ y,     // chunk-major [4][N][64] bf16 bits
    const int*    __restrict__ neigh, // [N][KFAN]
    float*        __restrict__ out)   // [N][FOUT] fp32
{
    const int bid   = blockIdx.x;
    const int chunk = bid & 3;
    const int nb    = bid >> 2;
    const int tid   = threadIdx.x;
    const int lane  = tid & 63;
    const int g     = lane >> 3;      // node-group within wave (0..7)
    const int gl    = lane & 7;       // lane within group
    const int wv    = tid >> 6;

    const int n  = nb * 32 + wv * 8 + g;
    const int nc = n < N_NODES ? n : N_NODES - 1;

    // group's 32 neighbor indices: lane gl holds idx[4gl .. 4gl+3]
    const i32x4 iv = __builtin_nontemporal_load(
        (const i32x4*)(neigh + (size_t)nc * KFAN + gl * 4));
    const int base8 = lane & 56;
    int ia[4] = {iv.x, iv.y, iv.z, iv.w};

    int idx[KFAN];
    #pragma unroll
    for (int k = 0; k < KFAN; ++k)
        idx[k] = __shfl(ia[k & 3], base8 + (k >> 2));

    const ushort* yc = y + (size_t)chunk * CHUNK_STRIDE + gl * 8;

    s16x8 acc = (s16x8)0;
    #pragma unroll
    for (int k = 0; k < KFAN; ++k) {
        s16x8 cur = *(const s16x8*)(yc + (size_t)idx[k] * 64);
        acc = __builtin_elementwise_max(acc, cur);
    }

    if (n < N_NODES) {
        f32x4 o0, o1;
        o0.x = __uint_as_float(((unsigned int)(ushort)acc[0]) << 16);
        o0.y = __uint_as_float(((unsigned int)(ushort)acc[1]) << 16);
        o0.z = __uint_as_float(((unsigned int)(ushort)acc[2]) << 16);
        o0.w = __uint_as_float(((unsigned int)(ushort)acc[3]) << 16);
        o1.x = __uint_as_float(((unsigned int)(ushort)acc[4]) << 16);
        o1.y = __uint_as_float(((unsigned int)(ushort)acc[5]) << 16);
        o1.z = __uint_as_float(((unsigned int)(ushort)acc[6]) << 16);
        o1.w = __uint_as_float(((unsigned int)(ushort)acc[7]) << 16);
        float* op = out + (size_t)n * FOUT + chunk * 64 + gl * 8;
        __builtin_nontemporal_store(o0, (f32x4*)op);
        __builtin_nontemporal_store(o1, (f32x4*)(op + 4));
    }
}

extern "C" void kernel_launch(void* const* d_in, const int* in_sizes, int n_in,
                              void* d_out, int out_size, void* d_ws, size_t ws_size,
                              hipStream_t stream) {
    const float* x     = (const float*)d_in[0];
    const int*   neigh = (const int*)  d_in[1];
    const float* W     = (const float*)d_in[2];
    const float* bias  = (const float*)d_in[3];
    float*       out   = (float*)d_out;
    ushort*      y     = (ushort*)d_ws;    // 12.8 MB of the 256 MiB ws
    // Park W^T (bf16, 128KB) at the front of d_out: gemm reads it, then
    // pool_max fully overwrites d_out afterwards (stream-ordered).
    ushort*      Wt    = (ushort*)d_out;

    transpose_w<<<64, 256, 0, stream>>>(W, Wt);

    dim3 g1((N_NODES + 63) / 64, 2);                       // (391, 2) = 782 blocks
    gemm_mfma<<<g1, 256, 0, stream>>>(x, Wt, bias, y);

    const int nblocks = ((N_NODES + 31) / 32) * 4;         // 782*4 = 3128
    pool_max<<<nblocks, 256, 0, stream>>>(y, neigh, out);
}